// Round 5
// baseline (158.886 us; speedup 1.0000x reference)
//
#include <hip/hip_runtime.h>
#include <hip/hip_bf16.h>

// Problem constants (B=16, S=2048, D=240, E=8, TOP_K=2)
#define TOKENS 32768
#define Dm 240
#define DP 256        // K (and N) padded to 256 for the bf16 staging buffers
#define NE 8
#define BK 32
#define NCHUNK 8      // K padded to 256 = 8 * 32
#define TILE_M 64
#define NB 64         // ordered expert-pair buckets (e0*8+e1)
#define CSTR 16       // cnt padding: one 64B cache line per counter

typedef __bf16 bf16x8 __attribute__((ext_vector_type(8)));
typedef float  f32x4  __attribute__((ext_vector_type(4)));

__device__ __forceinline__ float b2f(unsigned short u) {
    union { unsigned int i; float f; } v; v.i = ((unsigned int)u) << 16; return v.f;
}
__device__ __forceinline__ float b2f_lo(unsigned u) {
    union { unsigned int i; float f; } v; v.i = u << 16; return v.f;
}
__device__ __forceinline__ float b2f_hi(unsigned u) {
    union { unsigned int i; float f; } v; v.i = u & 0xFFFF0000u; return v.f;
}
__device__ __forceinline__ unsigned short f2b(float f) {
    unsigned int i = __builtin_bit_cast(unsigned int, f);
    unsigned int r = (i + 0x7FFFu + ((i >> 16) & 1u)) >> 16;   // RNE
    return (unsigned short)r;
}
__device__ __forceinline__ unsigned short f2h(float f) {
    _Float16 h = (_Float16)f;
    union { _Float16 h; unsigned short u; } v; v.h = h; return v.u;
}
__device__ __forceinline__ float h2f(unsigned short u) {
    union { _Float16 h; unsigned short u; } v; v.u = u; return (float)v.h;
}
__device__ __forceinline__ uint4 pack8(float4 a, float4 b) {
    union { unsigned short u[8]; uint4 v; } r;
    r.u[0] = f2b(a.x); r.u[1] = f2b(a.y); r.u[2] = f2b(a.z); r.u[3] = f2b(a.w);
    r.u[4] = f2b(b.x); r.u[5] = f2b(b.y); r.u[6] = f2b(b.z); r.u[7] = f2b(b.w);
    return r.v;
}

// Async global->LDS, 16B per lane. LDS dest is wave-uniform base + lane*16.
__device__ __forceinline__ void gload_lds16(const void* g, void* l) {
    __builtin_amdgcn_global_load_lds(
        (const __attribute__((address_space(1))) void*)g,
        (__attribute__((address_space(3))) void*)l,
        16, 0, 0);
}

// Per-block inline dtype detect: first 256 threads read the first 2048 ushorts
// of x. fp32 data read as ushorts has ~25% of mantissa-halves with huge bf16
// exponent; bf16 N(0,1) data has none.
__device__ __forceinline__ bool block_detect_f32(const unsigned short* x,
                                                 int tid, int* dh) {
    if (tid == 0) *dh = 0;
    __syncthreads();
    if (tid < 256) {
        uint4 q = *(const uint4*)&x[tid * 8];
        unsigned w[4] = {q.x, q.y, q.z, q.w};
        int hits = 0;
        #pragma unroll
        for (int i = 0; i < 4; i++) {
            if ((((w[i] & 0xFFFFu) >> 7) & 0xFFu) >= 0xC0u) hits++;
            if ((((w[i] >> 16)      >> 7) & 0xFFu) >= 0xC0u) hits++;
        }
        if (hits) atomicAdd(dh, hits);
    }
    __syncthreads();
    return *dh > 8;
}

// ---------------------------------------------------------------------------
// R15 wconv: self-detects dtype (block 0 publishes flag + zeroes the PADDED
// counters). Expert weights -> bf16, CHUNK-MAJOR layout matching the expert
// kernel's register-fragment addressing: wpad[e][c][slot][n][8]. Bias -> f32.
// ---------------------------------------------------------------------------
__global__ __launch_bounds__(256) void wconv_kernel(
    const void* __restrict__ ewv, const void* __restrict__ ebv,
    const unsigned short* __restrict__ xus,
    int* __restrict__ flag, int* __restrict__ cnt,
    unsigned short* __restrict__ wpad, float* __restrict__ ebpad)
{
    __shared__ int dh;
    int tid = threadIdx.x;
    const bool f32 = block_detect_f32(xus, tid, &dh);
    if (blockIdx.x == 0) {
        if (tid == 0) flag[0] = f32 ? 1 : 0;
        for (int i = tid; i < NB * CSTR; i += 256) cnt[i] = 0;
    }

    int gidx = blockIdx.x * 256 + tid;             // 0..65535, one 16B unit each

    if (gidx < NE * DP) {                          // bias: 2048 floats
        int e = gidx >> 8, n = gidx & 255;
        float bv = 0.f;
        if (n < Dm)
            bv = f32 ? ((const float*)ebv)[e * Dm + n]
                     : b2f(((const unsigned short*)ebv)[e * Dm + n]);
        ebpad[gidx] = bv;
    }

    // decompose: gidx = ((e*8 + c)*4 + s)*256 + n
    int n = gidx & 255;
    int s = (gidx >> 8) & 3;
    int c = (gidx >> 10) & 7;
    int e = gidx >> 13;
    int k = c * 32 + s * 8;
    uint4 v = make_uint4(0, 0, 0, 0);
    if (n < Dm && k < Dm) {
        if (f32) {
            const float* src = (const float*)ewv + ((long)e * Dm + n) * Dm + k;
            v = pack8(*(const float4*)src, *(const float4*)(src + 4));
        } else {
            v = *(const uint4*)((const unsigned short*)ewv + ((long)e * Dm + n) * Dm + k);
        }
    }
    *(uint4*)&wpad[(long)gidx * 8] = v;
}

// ---------------------------------------------------------------------------
// R15 gate: 256 blocks x 1024 threads (128 tokens/block, 8 lanes/token).
// Atomic-pressure fix vs R14: 4x fewer blocks -> 16K global atomics (R13-
// proven scale), counters padded to one cache line each (parallel L2 banks,
// no line ping-pong), block-staggered counter order. Math unchanged: lane j
// handles k-granules {j,j+8,j+16,j+24}; 3 shfl_xor rounds; leader does top-2
// + histogram/scatter. gw f32 in LDS on the fp32 path (top-2 fidelity).
// Fused x -> bf16 K-padded xpad write (granules 30,31 = zeros).
// ---------------------------------------------------------------------------
__global__ __launch_bounds__(1024) void gate_kernel(
    const void* __restrict__ xv, const void* __restrict__ gwv,
    const void* __restrict__ gbv,
    int* __restrict__ cnt, unsigned* __restrict__ rt,
    unsigned short* __restrict__ xpad)
{
    __shared__ float gwsF[NE * Dm];     // 7680 B (f32 path); bf16 path uses 1/2
    __shared__ int h[NB];
    __shared__ int base[NB];
    __shared__ int dh;

    int tid = threadIdx.x;
    if (tid < NB) h[tid] = 0;
    const bool f32 = block_detect_f32((const unsigned short*)xv, tid, &dh);

    // stage gate weights
    if (f32) {
        if (tid < 240) {
            const float* s = (const float*)gwv + tid * 8;
            float4 a = *(const float4*)s;
            float4 b4 = *(const float4*)(s + 4);
            float* d = &gwsF[tid * 8];
            *(float4*)d = a; *(float4*)(d + 4) = b4;
        }
    } else {
        if (tid < 240) {
            unsigned short* gb16 = (unsigned short*)gwsF;
            *(uint4*)&gb16[tid * 8] =
                *(const uint4*)((const unsigned short*)gwv + tid * 8);
        }
    }
    __syncthreads();

    int grp = tid >> 3;            // 0..127: token group within block
    int j   = tid & 7;             // lane within group
    int t   = blockIdx.x * 128 + grp;

    float acc[NE] = {0.f, 0.f, 0.f, 0.f, 0.f, 0.f, 0.f, 0.f};
    unsigned short* xo = xpad + (long)t * DP;

    if (f32) {
        const float* xf = (const float*)xv + (long)t * Dm;
        #pragma unroll
        for (int i = 0; i < 4; i++) {
            int g = j + 8 * i;                 // granule: 8 elems
            if (g < 30) {
                float4 xa = *(const float4*)&xf[g * 8];
                float4 xb = *(const float4*)&xf[g * 8 + 4];
                *(uint4*)&xo[g * 8] = pack8(xa, xb);
                #pragma unroll
                for (int e = 0; e < NE; e++) {
                    const float* gp = &gwsF[e * Dm + g * 8];
                    float4 ga = *(const float4*)gp;
                    float4 gc = *(const float4*)(gp + 4);
                    acc[e] += xa.x * ga.x + xa.y * ga.y + xa.z * ga.z + xa.w * ga.w
                            + xb.x * gc.x + xb.y * gc.y + xb.z * gc.z + xb.w * gc.w;
                }
            } else {
                *(uint4*)&xo[g * 8] = make_uint4(0, 0, 0, 0);   // K pad
            }
        }
    } else {
        const unsigned short* xb = (const unsigned short*)xv + (long)t * Dm;
        const unsigned short* gb16 = (const unsigned short*)gwsF;
        #pragma unroll
        for (int i = 0; i < 4; i++) {
            int g = j + 8 * i;
            if (g < 30) {
                uint4 xq = *(const uint4*)&xb[g * 8];
                *(uint4*)&xo[g * 8] = xq;
                float x0 = b2f_lo(xq.x), x1 = b2f_hi(xq.x);
                float x2 = b2f_lo(xq.y), x3 = b2f_hi(xq.y);
                float x4 = b2f_lo(xq.z), x5 = b2f_hi(xq.z);
                float x6 = b2f_lo(xq.w), x7 = b2f_hi(xq.w);
                #pragma unroll
                for (int e = 0; e < NE; e++) {
                    uint4 gq = *(const uint4*)&gb16[e * Dm + g * 8];
                    acc[e] += x0 * b2f_lo(gq.x) + x1 * b2f_hi(gq.x)
                            + x2 * b2f_lo(gq.y) + x3 * b2f_hi(gq.y)
                            + x4 * b2f_lo(gq.z) + x5 * b2f_hi(gq.z)
                            + x6 * b2f_lo(gq.w) + x7 * b2f_hi(gq.w);
                }
            } else {
                *(uint4*)&xo[g * 8] = make_uint4(0, 0, 0, 0);   // K pad
            }
        }
    }

    // reduce partial dots across the 8 lanes of the group (all lanes get sum)
    #pragma unroll
    for (int m = 1; m < 8; m <<= 1)
        #pragma unroll
        for (int e = 0; e < NE; e++)
            acc[e] += __shfl_xor(acc[e], m, 64);

    int bb = 0; float w0 = 0.f;
    if (j == 0) {
        #pragma unroll
        for (int e = 0; e < NE; e++)
            acc[e] += f32 ? ((const float*)gbv)[e]
                          : b2f(((const unsigned short*)gbv)[e]);
        // top-2 (strict > keeps lowest index on ties, matching lax.top_k)
        float l0 = -1e30f; int e0 = 0;
        #pragma unroll
        for (int e = 0; e < NE; e++) if (acc[e] > l0) { l0 = acc[e]; e0 = e; }
        float l1 = -1e30f; int e1 = 0;
        #pragma unroll
        for (int e = 0; e < NE; e++) if (e != e0 && acc[e] > l1) { l1 = acc[e]; e1 = e; }
        w0 = 1.f / (1.f + __expf(l1 - l0));   // renormalized top-2 softmax
        bb = e0 * 8 + e1;                      // ordered pair bucket
        atomicAdd(&h[bb], 1);
    }
    __syncthreads();
    if (tid < NB) {
        int i = (tid + blockIdx.x) & (NB - 1);   // stagger start counter
        int c = h[i];
        if (c) base[i] = atomicAdd(&cnt[i * CSTR], c);
        h[i] = 0;
    }
    __syncthreads();
    if (j == 0) {
        int o = atomicAdd(&h[bb], 1);
        rt[bb * TOKENS + base[bb] + o] = ((unsigned)t << 16) | (unsigned)f2h(w0);
    }
}

// ---------------------------------------------------------------------------
// R15 expert: barrier-free K-loop (R14-proven) minus the cntS LDS stage --
// padded counters are read directly (uniform scalar loads, L2-hot). X staged
// once for all 8 chunks via global_load_lds (32 KB, ONE barrier); W loaded
// straight to VGPRs from chunk-major wpad. Both experts of the pair-bucket
// computed, out written ONCE. Bijective XCD swizzle for W L2 locality.
// ---------------------------------------------------------------------------
__global__ __launch_bounds__(256, 2) void expert_kernel(
    const unsigned short* __restrict__ xp,   // [TOKENS][256] bf16 K-padded
    const unsigned short* __restrict__ wp,   // [8][8 c][4 s][256 n][8] bf16
    const float* __restrict__ ebpad,         // [8][256] f32
    const int* __restrict__ flag,
    const int* __restrict__ cnt, const unsigned* __restrict__ rt,
    void* __restrict__ outv)
{
    __shared__ __align__(16) unsigned short Xc[NCHUNK][4][64][8];  // 32 KB

    const bool f32o = (*flag != 0);
    int tid = threadIdx.x;

    // XCD-aware bijective swizzle (gridDim.x % 8 == 0 by construction)
    int nwg = gridDim.x;
    int fid = blockIdx.x;
    if ((nwg & 7) == 0)
        fid = (blockIdx.x & 7) * (nwg >> 3) + (blockIdx.x >> 3);

    // flat tile id -> (bucket, tile); padded counters, uniform scalar loads
    int b = -1, t = 0, accn = 0, ne = 0;
    for (int i = 0; i < NB; i++) {
        int ci = cnt[i * CSTR];
        int ti = (ci + 63) >> 6;
        if (fid < accn + ti) { b = i; t = fid - accn; ne = ci; break; }
        accn += ti;
    }
    if (b < 0) return;
    int e0 = b >> 3, e1 = b & 7;
    int m0 = t * TILE_M;
    int rows = min(TILE_M, ne - m0);

    int lane = tid & 63;
    int wv   = tid >> 6;          // wave id = k-slot owner for X staging

    // token list in registers: lane l holds tile-row l
    unsigned rvp = rt[b * TOKENS + min(m0 + lane, ne - 1)];
    int   tokL = (int)(rvp >> 16);
    float w0L  = h2f((unsigned short)(rvp & 0xFFFFu));

    // stage ALL X chunks (lane l -> Xc[c][wv][l][:]), one barrier total
    const unsigned short* xsrc = xp + (long)tokL * DP + wv * 8;
    #pragma unroll
    for (int c = 0; c < NCHUNK; c++)
        gload_lds16(xsrc + c * BK, &Xc[c][wv][0][0]);
    __syncthreads();

    int frow = lane & 15;
    int slot = lane >> 4;
    // W fragment bases: elem off = e*65536 + c*8192 + slot*2048 + n*8
    const unsigned short* wb0 = wp + (long)e0 * 65536 + slot * 2048
                                   + (wv * 64 + frow) * 8;
    const unsigned short* wb1 = wp + (long)e1 * 65536 + slot * 2048
                                   + (wv * 64 + frow) * 8;

    f32x4 acc0[4][4] = {};
    f32x4 acc1[4][4] = {};

    #pragma unroll
    for (int c = 0; c < NCHUNK; c++) {
        bf16x8 a[4], b0[4], b1[4];
        #pragma unroll
        for (int mt = 0; mt < 4; mt++)
            a[mt] = *(const bf16x8*)&Xc[c][slot][mt * 16 + frow][0];
        #pragma unroll
        for (int nt = 0; nt < 4; nt++) {
            b0[nt] = *(const bf16x8*)&wb0[c * 8192 + nt * 128];
            b1[nt] = *(const bf16x8*)&wb1[c * 8192 + nt * 128];
        }
        #pragma unroll
        for (int nt = 0; nt < 4; nt++)
            #pragma unroll
            for (int mt = 0; mt < 4; mt++) {
                acc0[mt][nt] = __builtin_amdgcn_mfma_f32_16x16x32_bf16(
                    a[mt], b0[nt], acc0[mt][nt], 0, 0, 0);
                acc1[mt][nt] = __builtin_amdgcn_mfma_f32_16x16x32_bf16(
                    a[mt], b1[nt], acc1[mt][nt], 0, 0, 0);
            }
    }

    // Epilogue: C/D layout col=lane&15, row=(lane>>4)*4+r  [m89-verified]
    int colg = lane & 15;
    int rq   = (lane >> 4) << 2;
    float b0n[4], b1n[4];
    #pragma unroll
    for (int nt = 0; nt < 4; nt++) {
        int n = wv * 64 + nt * 16 + colg;
        b0n[nt] = ebpad[e0 * DP + n];
        b1n[nt] = ebpad[e1 * DP + n];
    }
    #pragma unroll
    for (int mt = 0; mt < 4; mt++) {
        #pragma unroll
        for (int r = 0; r < 4; r++) {
            int m = mt * 16 + rq + r;
            int   tok = __shfl(tokL, m);   // all lanes active here
            float w0  = __shfl(w0L, m);
            float w1  = 1.f - w0;
            if (m < rows) {
                #pragma unroll
                for (int nt = 0; nt < 4; nt++) {
                    int n = wv * 64 + nt * 16 + colg;
                    if (n < Dm) {
                        float val = (acc0[mt][nt][r] + b0n[nt]) * w0
                                  + (acc1[mt][nt][r] + b1n[nt]) * w1;
                        long idx = (long)tok * Dm + n;
                        if (f32o) ((float*)outv)[idx] = val;
                        else      ((unsigned short*)outv)[idx] = f2b(val);
                    }
                }
            }
        }
    }
}

// ---------------------------------------------------------------------------
// Fallback path (R10-proven) for small workspaces — unchanged.
// ---------------------------------------------------------------------------
__global__ void detect_kernel(const unsigned short* __restrict__ x, int* flag,
                              int* __restrict__ cnt) {
    int lane = threadIdx.x;   // 64 threads
    cnt[lane] = 0;
    int hits = 0;
    for (int i = lane; i < 2048; i += 64) {
        unsigned e = (x[i] >> 7) & 0xFFu;
        if (e >= 0xC0u) hits++;
    }
    #pragma unroll
    for (int off = 32; off >= 1; off >>= 1) hits += __shfl_xor(hits, off, 64);
    if (lane == 0) flag[0] = (hits > 8) ? 1 : 0;
}

__global__ void init_kernel(int* cnt) {
    if (threadIdx.x < 16) cnt[threadIdx.x] = 0;
}

__global__ void zero_kernel(void* outv, const int* flag, int nelem) {
    long i = (long)blockIdx.x * blockDim.x + threadIdx.x;
    long stride = (long)gridDim.x * blockDim.x;
    if (*flag) {
        float* o = (float*)outv;
        for (; i < nelem; i += stride) o[i] = 0.f;
    } else {
        unsigned* o = (unsigned*)outv;
        long n = nelem >> 1;
        for (; i < n; i += stride) o[i] = 0u;
    }
}

template<bool FP32>
__global__ __launch_bounds__(256) void gate_fb_kernel(
    const void* __restrict__ xv, const void* __restrict__ gwv,
    const void* __restrict__ gbv, const int* __restrict__ flag,
    int* __restrict__ cnt, unsigned* __restrict__ rt, int cap)
{
    if ((*flag != 0) != FP32) return;
    __shared__ unsigned rv[256];
    __shared__ int h[16];
    __shared__ int base[16];

    int tid = threadIdx.x;
    if (tid < 16) h[tid] = 0;
    int t = blockIdx.x * 256 + tid;

    float acc[NE];
    #pragma unroll
    for (int e = 0; e < NE; e++)
        acc[e] = FP32 ? ((const float*)gbv)[e]
                      : b2f(((const unsigned short*)gbv)[e]);

    if (FP32) {
        const float* xf  = (const float*)xv + (long)t * Dm;
        const float* gwf = (const float*)gwv;
        for (int k = 0; k < Dm; k += 8) {
            float4 xa = *(const float4*)&xf[k];
            float4 xb = *(const float4*)&xf[k + 4];
            #pragma unroll
            for (int e = 0; e < NE; e++) {
                float4 ga = *(const float4*)&gwf[e * Dm + k];
                float4 gb = *(const float4*)&gwf[e * Dm + k + 4];
                acc[e] += xa.x * ga.x + xa.y * ga.y + xa.z * ga.z + xa.w * ga.w
                        + xb.x * gb.x + xb.y * gb.y + xb.z * gb.z + xb.w * gb.w;
            }
        }
    } else {
        const unsigned short* xb  = (const unsigned short*)xv + (long)t * Dm;
        const unsigned short* gwb = (const unsigned short*)gwv;
        for (int k = 0; k < Dm; k += 8) {
            uint4 xq = *(const uint4*)&xb[k];
            float x0 = b2f_lo(xq.x), x1 = b2f_hi(xq.x);
            float x2 = b2f_lo(xq.y), x3 = b2f_hi(xq.y);
            float x4 = b2f_lo(xq.z), x5 = b2f_hi(xq.z);
            float x6 = b2f_lo(xq.w), x7 = b2f_hi(xq.w);
            #pragma unroll
            for (int e = 0; e < NE; e++) {
                uint4 gq = *(const uint4*)&gwb[e * Dm + k];
                acc[e] += x0 * b2f_lo(gq.x) + x1 * b2f_hi(gq.x)
                        + x2 * b2f_lo(gq.y) + x3 * b2f_hi(gq.y)
                        + x4 * b2f_lo(gq.z) + x5 * b2f_hi(gq.z)
                        + x6 * b2f_lo(gq.w) + x7 * b2f_hi(gq.w);
            }
        }
    }

    float l0 = -1e30f; int e0 = 0;
    #pragma unroll
    for (int e = 0; e < NE; e++) if (acc[e] > l0) { l0 = acc[e]; e0 = e; }
    float l1 = -1e30f; int e1 = 0;
    #pragma unroll
    for (int e = 0; e < NE; e++) if (e != e0 && acc[e] > l1) { l1 = acc[e]; e1 = e; }
    float w0 = 1.f / (1.f + __expf(l1 - l0));

    rv[tid] = ((unsigned)e1 << 20) | ((unsigned)e0 << 16) | (unsigned)f2h(w0);
    __syncthreads();

    {
        unsigned v = rv[tid];
        atomicAdd(&h[(v >> 16) & 7], 1);
        atomicAdd(&h[8 + ((v >> 20) & 7)], 1);
    }
    __syncthreads();

    if (tid < 16) {
        base[tid] = atomicAdd(&cnt[tid], h[tid]);
        h[tid] = 0;
    }
    __syncthreads();

    {
        unsigned v = rv[tid];
        int tt = blockIdx.x * 256 + tid;
        int a0 = (v >> 16) & 7;
        int a1 = (v >> 20) & 7;
        unsigned short hw0 = (unsigned short)(v & 0xFFFFu);
        int o0 = atomicAdd(&h[a0], 1);
        int p0 = base[a0] + o0;
        if (p0 < cap) rt[a0 * cap + p0] = ((unsigned)tt << 16) | hw0;
        int o1 = atomicAdd(&h[8 + a1], 1);
        int p1 = base[8 + a1] + o1;
        if (p1 < cap) rt[(8 + a1) * cap + p1] = ((unsigned)tt << 16) | (unsigned)f2h(1.f - h2f(hw0));
    }
}

template<bool FP32>
__global__ __launch_bounds__(256) void expert_fb_kernel(
    const void* __restrict__ xv, const void* __restrict__ ewv,
    const void* __restrict__ ebv, const int* __restrict__ flag,
    const int* __restrict__ cnt, const unsigned* __restrict__ rt, int cap,
    void* __restrict__ outv, int slotBase, int accumulate)
{
    if ((*flag != 0) != FP32) return;
    int e = blockIdx.y;
    int tile = blockIdx.x;
    int bucket = slotBase + e;
    int ne = min(cnt[bucket], cap);
    int m0 = tile * TILE_M;
    if (m0 >= ne) return;
    int rows = min(TILE_M, ne - m0);

    __shared__ __align__(16) unsigned short Wcf[2][256][40];
    __shared__ __align__(16) unsigned short Xcf[2][TILE_M][40];
    __shared__ int   tokS[TILE_M];
    __shared__ float twS[TILE_M];

    int tid = threadIdx.x;
    if (tid < TILE_M) {
        int i = min(m0 + tid, ne - 1);
        unsigned v = rt[bucket * cap + i];
        tokS[tid] = (int)(v >> 16);
        twS[tid]  = (tid < rows) ? h2f((unsigned short)(v & 0xFFFFu)) : 0.f;
    }
    __syncthreads();

    int srow = tid >> 2;
    int part = tid & 3;

    auto stage = [&](int c, int buf) {
        int kk = c * BK + part * 8;
        bool kvalid = (kk < Dm);
        if (FP32) {
            const float* xf = (const float*)xv;
            const float* Wf = (const float*)ewv + e * Dm * Dm;
            uint4 xq = make_uint4(0, 0, 0, 0);
            if (kvalid) {
                const float* s = &xf[(long)tokS[srow] * Dm + kk];
                xq = pack8(*(const float4*)s, *(const float4*)(s + 4));
            }
            *(uint4*)&Xcf[buf][srow][part * 8] = xq;
            #pragma unroll
            for (int it = 0; it < 4; it++) {
                int n = srow + it * 64;
                uint4 wq = make_uint4(0, 0, 0, 0);
                if (kvalid && n < Dm) {
                    const float* s = &Wf[(long)n * Dm + kk];
                    wq = pack8(*(const float4*)s, *(const float4*)(s + 4));
                }
                *(uint4*)&Wcf[buf][n][part * 8] = wq;
            }
        } else {
            const unsigned short* xb = (const unsigned short*)xv;
            const unsigned short* Wb = (const unsigned short*)ewv + e * Dm * Dm;
            uint4 xq = make_uint4(0, 0, 0, 0);
            if (kvalid) xq = *(const uint4*)&xb[(long)tokS[srow] * Dm + kk];
            *(uint4*)&Xcf[buf][srow][part * 8] = xq;
            #pragma unroll
            for (int it = 0; it < 4; it++) {
                int n = srow + it * 64;
                uint4 wq = make_uint4(0, 0, 0, 0);
                if (kvalid && n < Dm) wq = *(const uint4*)&Wb[(long)n * Dm + kk];
                *(uint4*)&Wcf[buf][n][part * 8] = wq;
            }
        }
    };

    int lane = tid & 63;
    int wv   = tid >> 6;
    int frow = lane & 15;
    int koff = (lane >> 4) * 8;

    f32x4 acc[TILE_M / 16][4] = {};

    stage(0, 0);
    __syncthreads();
    for (int c = 0; c < NCHUNK; c++) {
        int buf = c & 1;
        bf16x8 a[TILE_M / 16], b[4];
        #pragma unroll
        for (int mt = 0; mt < TILE_M / 16; mt++)
            a[mt] = *(const bf16x8*)&Xcf[buf][mt * 16 + frow][koff];
        #pragma unroll
        for (int nt = 0; nt < 4; nt++)
            b[nt] = *(const bf16x8*)&Wcf[buf][wv * 64 + nt * 16 + frow][koff];
        if (c + 1 < NCHUNK) stage(c + 1, (c + 1) & 1);
        #pragma unroll
        for (int mt = 0; mt < TILE_M / 16; mt++)
            #pragma unroll
            for (int nt = 0; nt < 4; nt++)
                acc[mt][nt] = __builtin_amdgcn_mfma_f32_16x16x32_bf16(
                    a[mt], b[nt], acc[mt][nt], 0, 0, 0);
        __syncthreads();
    }

    int colg  = lane & 15;
    int rquad = (lane >> 4) * 4;
    #pragma unroll
    for (int nt = 0; nt < 4; nt++) {
        int n = wv * 64 + nt * 16 + colg;
        if (n >= Dm) continue;
        float bnv = FP32 ? ((const float*)ebv)[e * Dm + n]
                         : b2f(((const unsigned short*)ebv)[e * Dm + n]);
        #pragma unroll
        for (int mt = 0; mt < TILE_M / 16; mt++) {
            #pragma unroll
            for (int r = 0; r < 4; r++) {
                int m = mt * 16 + rquad + r;
                if (m < rows) {
                    float val = (acc[mt][nt][r] + bnv) * twS[m];
                    long idx = (long)tokS[m] * Dm + n;
                    if (FP32) {
                        float* o = (float*)outv + idx;
                        *o = accumulate ? (*o + val) : val;
                    } else {
                        unsigned short* o = (unsigned short*)outv + idx;
                        *o = accumulate ? f2b(b2f(*o) + val) : f2b(val);
                    }
                }
            }
        }
    }
}

extern "C" void kernel_launch(void* const* d_in, const int* in_sizes, int n_in,
                              void* d_out, int out_size, void* d_ws, size_t ws_size,
                              hipStream_t stream) {
    const void* x  = d_in[0];
    const void* gw = d_in[1];
    const void* gb = d_in[2];
    const void* ew = d_in[3];
    const void* eb = d_in[4];

    char* ws = (char*)d_ws;
    int* flag = (int*)ws;                 // [0]        dtype flag
    int* cnt  = (int*)(ws + 64);          // [64*CSTR]  padded bucket counters

    // R15 fast-path workspace layout
    const size_t EB_OFF = 64 + (size_t)NB * CSTR * 4;            // 4160
    const size_t RT_OFF = EB_OFF + (size_t)NE * DP * 4;          // 12352
    const size_t XP_OFF = RT_OFF + (size_t)NB * TOKENS * 4;      // +8 MiB
    const size_t WP_OFF = XP_OFF + (size_t)TOKENS * DP * 2;      // +16 MiB
    const size_t NEEDED = WP_OFF + (size_t)NE * NCHUNK * 8192 * 2; // ≈ 26.2 MB

    if (ws_size >= NEEDED) {
        float*          ebpad = (float*)(ws + EB_OFF);
        unsigned*       rt    = (unsigned*)(ws + RT_OFF);
        unsigned short* xpad  = (unsigned short*)(ws + XP_OFF);
        unsigned short* wpad  = (unsigned short*)(ws + WP_OFF);

        wconv_kernel<<<256, 256, 0, stream>>>(ew, eb, (const unsigned short*)x,
                                              flag, cnt, wpad, ebpad);
        gate_kernel<<<TOKENS / 128, 1024, 0, stream>>>(x, gw, gb, cnt, rt, xpad);
        // worst-case flat tiles: 32768/64 full + 64 partials = 576 (mult of 8)
        expert_kernel<<<TOKENS / TILE_M + NB, 256, 0, stream>>>(
            xpad, wpad, ebpad, flag, cnt, rt, d_out);
    } else {
        // ---------------- R10 fallback (proven) ----------------
        unsigned* rt = (unsigned*)(ws + 128);
        long capl = ((long)ws_size - 128) / (16 * sizeof(unsigned));
        if (capl > TOKENS) capl = TOKENS;
        if (capl < 64) capl = 64;
        int cap = (int)capl;
        int tiles = (cap + TILE_M - 1) / TILE_M;
        bool lossless = (cap >= TOKENS);
        int acc0 = lossless ? 0 : 1;

        detect_kernel<<<1, 64, 0, stream>>>((const unsigned short*)x, flag, cnt);
        init_kernel<<<1, 64, 0, stream>>>(cnt);
        gate_fb_kernel<false><<<TOKENS / 256, 256, 0, stream>>>(x, gw, gb, flag, cnt, rt, cap);
        gate_fb_kernel<true ><<<TOKENS / 256, 256, 0, stream>>>(x, gw, gb, flag, cnt, rt, cap);
        if (!lossless)
            zero_kernel<<<1024, 256, 0, stream>>>(d_out, flag, out_size);
        expert_fb_kernel<false><<<dim3(tiles, NE), 256, 0, stream>>>(x, ew, eb, flag, cnt, rt, cap, d_out, 0, acc0);
        expert_fb_kernel<true ><<<dim3(tiles, NE), 256, 0, stream>>>(x, ew, eb, flag, cnt, rt, cap, d_out, 0, acc0);
        expert_fb_kernel<false><<<dim3(tiles, NE), 256, 0, stream>>>(x, ew, eb, flag, cnt, rt, cap, d_out, 8, 1);
        expert_fb_kernel<true ><<<dim3(tiles, NE), 256, 0, stream>>>(x, ew, eb, flag, cnt, rt, cap, d_out, 8, 1);
    }
}

// Round 6
// 140.110 us; speedup vs baseline: 1.1340x; 1.1340x over previous
//
#include <hip/hip_runtime.h>
#include <hip/hip_bf16.h>

// Problem constants (B=16, S=2048, D=240, E=8, TOP_K=2)
#define TOKENS 32768
#define Dm 240
#define DP 256        // K (and N) padded to 256 for the bf16 staging buffers
#define NE 8
#define BK 32
#define NCHUNK 8      // K padded to 256 = 8 * 32
#define TILE_M 64
#define NB 64         // ordered expert-pair buckets (e0*8+e1)
#define CSTR 16       // cnt padding: one 64B cache line per counter

typedef __bf16 bf16x8 __attribute__((ext_vector_type(8)));
typedef float  f32x4  __attribute__((ext_vector_type(4)));

__device__ __forceinline__ float b2f(unsigned short u) {
    union { unsigned int i; float f; } v; v.i = ((unsigned int)u) << 16; return v.f;
}
__device__ __forceinline__ float b2f_lo(unsigned u) {
    union { unsigned int i; float f; } v; v.i = u << 16; return v.f;
}
__device__ __forceinline__ float b2f_hi(unsigned u) {
    union { unsigned int i; float f; } v; v.i = u & 0xFFFF0000u; return v.f;
}
__device__ __forceinline__ unsigned short f2b(float f) {
    unsigned int i = __builtin_bit_cast(unsigned int, f);
    unsigned int r = (i + 0x7FFFu + ((i >> 16) & 1u)) >> 16;   // RNE
    return (unsigned short)r;
}
__device__ __forceinline__ unsigned short f2h(float f) {
    _Float16 h = (_Float16)f;
    union { _Float16 h; unsigned short u; } v; v.h = h; return v.u;
}
__device__ __forceinline__ float h2f(unsigned short u) {
    union { _Float16 h; unsigned short u; } v; v.u = u; return (float)v.h;
}
__device__ __forceinline__ uint4 pack8(float4 a, float4 b) {
    union { unsigned short u[8]; uint4 v; } r;
    r.u[0] = f2b(a.x); r.u[1] = f2b(a.y); r.u[2] = f2b(a.z); r.u[3] = f2b(a.w);
    r.u[4] = f2b(b.x); r.u[5] = f2b(b.y); r.u[6] = f2b(b.z); r.u[7] = f2b(b.w);
    return r.v;
}

// Async global->LDS, 16B per lane. LDS dest is wave-uniform base + lane*16.
__device__ __forceinline__ void gload_lds16(const void* g, void* l) {
    __builtin_amdgcn_global_load_lds(
        (const __attribute__((address_space(1))) void*)g,
        (__attribute__((address_space(3))) void*)l,
        16, 0, 0);
}

// Per-block inline dtype detect: first 256 threads read the first 2048 ushorts
// of x. fp32 data read as ushorts has ~25% of mantissa-halves with huge bf16
// exponent; bf16 N(0,1) data has none.
__device__ __forceinline__ bool block_detect_f32(const unsigned short* x,
                                                 int tid, int* dh) {
    if (tid == 0) *dh = 0;
    __syncthreads();
    if (tid < 256) {
        uint4 q = *(const uint4*)&x[tid * 8];
        unsigned w[4] = {q.x, q.y, q.z, q.w};
        int hits = 0;
        #pragma unroll
        for (int i = 0; i < 4; i++) {
            if ((((w[i] & 0xFFFFu) >> 7) & 0xFFu) >= 0xC0u) hits++;
            if ((((w[i] >> 16)      >> 7) & 0xFFu) >= 0xC0u) hits++;
        }
        if (hits) atomicAdd(dh, hits);
    }
    __syncthreads();
    return *dh > 8;
}

// ---------------------------------------------------------------------------
// R16 wconv: self-detects dtype (block 0 publishes flag + zeroes the PADDED
// counters). Expert weights -> bf16, CHUNK-MAJOR layout matching the expert
// kernel's register-fragment addressing: wpad[e][c][slot][n][8]. Bias -> f32.
// ---------------------------------------------------------------------------
__global__ __launch_bounds__(256) void wconv_kernel(
    const void* __restrict__ ewv, const void* __restrict__ ebv,
    const unsigned short* __restrict__ xus,
    int* __restrict__ flag, int* __restrict__ cnt,
    unsigned short* __restrict__ wpad, float* __restrict__ ebpad)
{
    __shared__ int dh;
    int tid = threadIdx.x;
    const bool f32 = block_detect_f32(xus, tid, &dh);
    if (blockIdx.x == 0) {
        if (tid == 0) flag[0] = f32 ? 1 : 0;
        for (int i = tid; i < NB * CSTR; i += 256) cnt[i] = 0;
    }

    int gidx = blockIdx.x * 256 + tid;             // 0..65535, one 16B unit each

    if (gidx < NE * DP) {                          // bias: 2048 floats
        int e = gidx >> 8, n = gidx & 255;
        float bv = 0.f;
        if (n < Dm)
            bv = f32 ? ((const float*)ebv)[e * Dm + n]
                     : b2f(((const unsigned short*)ebv)[e * Dm + n]);
        ebpad[gidx] = bv;
    }

    // decompose: gidx = ((e*8 + c)*4 + s)*256 + n
    int n = gidx & 255;
    int s = (gidx >> 8) & 3;
    int c = (gidx >> 10) & 7;
    int e = gidx >> 13;
    int k = c * 32 + s * 8;
    uint4 v = make_uint4(0, 0, 0, 0);
    if (n < Dm && k < Dm) {
        if (f32) {
            const float* src = (const float*)ewv + ((long)e * Dm + n) * Dm + k;
            v = pack8(*(const float4*)src, *(const float4*)(src + 4));
        } else {
            v = *(const uint4*)((const unsigned short*)ewv + ((long)e * Dm + n) * Dm + k);
        }
    }
    *(uint4*)&wpad[(long)gidx * 8] = v;
}

// ---------------------------------------------------------------------------
// R16 gate: byte-identical revert to the R14-proven shape (1024 blocks x 256
// threads, 8 lanes/token, 32 tokens/block) with ONLY the atomic layout
// changed: counters padded to one cache line each + block-staggered order.
// Lane j handles k-granules {j,j+8,j+16,j+24}; 3 shfl_xor rounds; leader
// does top-2 + histogram/scatter. gw f32 in LDS on the fp32 path.
// Fused x -> bf16 K-padded xpad write (granules 30,31 = zeros).
// ---------------------------------------------------------------------------
__global__ __launch_bounds__(256) void gate_kernel(
    const void* __restrict__ xv, const void* __restrict__ gwv,
    const void* __restrict__ gbv,
    int* __restrict__ cnt, unsigned* __restrict__ rt,
    unsigned short* __restrict__ xpad)
{
    __shared__ float gwsF[NE * Dm];     // 7680 B (f32 path); bf16 path uses 1/2
    __shared__ int h[NB];
    __shared__ int base[NB];
    __shared__ int dh;

    int tid = threadIdx.x;
    if (tid < NB) h[tid] = 0;
    const bool f32 = block_detect_f32((const unsigned short*)xv, tid, &dh);

    // stage gate weights
    if (f32) {
        if (tid < 240) {
            const float* s = (const float*)gwv + tid * 8;
            float4 a = *(const float4*)s;
            float4 b4 = *(const float4*)(s + 4);
            float* d = &gwsF[tid * 8];
            *(float4*)d = a; *(float4*)(d + 4) = b4;
        }
    } else {
        if (tid < 240) {
            unsigned short* gb16 = (unsigned short*)gwsF;
            *(uint4*)&gb16[tid * 8] =
                *(const uint4*)((const unsigned short*)gwv + tid * 8);
        }
    }
    __syncthreads();

    int grp = tid >> 3;            // 0..31: token group within block
    int j   = tid & 7;             // lane within group
    int t   = blockIdx.x * 32 + grp;

    float acc[NE] = {0.f, 0.f, 0.f, 0.f, 0.f, 0.f, 0.f, 0.f};
    unsigned short* xo = xpad + (long)t * DP;

    if (f32) {
        const float* xf = (const float*)xv + (long)t * Dm;
        #pragma unroll
        for (int i = 0; i < 4; i++) {
            int g = j + 8 * i;                 // granule: 8 elems
            if (g < 30) {
                float4 xa = *(const float4*)&xf[g * 8];
                float4 xb = *(const float4*)&xf[g * 8 + 4];
                *(uint4*)&xo[g * 8] = pack8(xa, xb);
                #pragma unroll
                for (int e = 0; e < NE; e++) {
                    const float* gp = &gwsF[e * Dm + g * 8];
                    float4 ga = *(const float4*)gp;
                    float4 gc = *(const float4*)(gp + 4);
                    acc[e] += xa.x * ga.x + xa.y * ga.y + xa.z * ga.z + xa.w * ga.w
                            + xb.x * gc.x + xb.y * gc.y + xb.z * gc.z + xb.w * gc.w;
                }
            } else {
                *(uint4*)&xo[g * 8] = make_uint4(0, 0, 0, 0);   // K pad
            }
        }
    } else {
        const unsigned short* xb = (const unsigned short*)xv + (long)t * Dm;
        const unsigned short* gb16 = (const unsigned short*)gwsF;
        #pragma unroll
        for (int i = 0; i < 4; i++) {
            int g = j + 8 * i;
            if (g < 30) {
                uint4 xq = *(const uint4*)&xb[g * 8];
                *(uint4*)&xo[g * 8] = xq;
                float x0 = b2f_lo(xq.x), x1 = b2f_hi(xq.x);
                float x2 = b2f_lo(xq.y), x3 = b2f_hi(xq.y);
                float x4 = b2f_lo(xq.z), x5 = b2f_hi(xq.z);
                float x6 = b2f_lo(xq.w), x7 = b2f_hi(xq.w);
                #pragma unroll
                for (int e = 0; e < NE; e++) {
                    uint4 gq = *(const uint4*)&gb16[e * Dm + g * 8];
                    acc[e] += x0 * b2f_lo(gq.x) + x1 * b2f_hi(gq.x)
                            + x2 * b2f_lo(gq.y) + x3 * b2f_hi(gq.y)
                            + x4 * b2f_lo(gq.z) + x5 * b2f_hi(gq.z)
                            + x6 * b2f_lo(gq.w) + x7 * b2f_hi(gq.w);
                }
            } else {
                *(uint4*)&xo[g * 8] = make_uint4(0, 0, 0, 0);   // K pad
            }
        }
    }

    // reduce partial dots across the 8 lanes of the group (all lanes get sum)
    #pragma unroll
    for (int m = 1; m < 8; m <<= 1)
        #pragma unroll
        for (int e = 0; e < NE; e++)
            acc[e] += __shfl_xor(acc[e], m, 64);

    int bb = 0; float w0 = 0.f;
    if (j == 0) {
        #pragma unroll
        for (int e = 0; e < NE; e++)
            acc[e] += f32 ? ((const float*)gbv)[e]
                          : b2f(((const unsigned short*)gbv)[e]);
        // top-2 (strict > keeps lowest index on ties, matching lax.top_k)
        float l0 = -1e30f; int e0 = 0;
        #pragma unroll
        for (int e = 0; e < NE; e++) if (acc[e] > l0) { l0 = acc[e]; e0 = e; }
        float l1 = -1e30f; int e1 = 0;
        #pragma unroll
        for (int e = 0; e < NE; e++) if (e != e0 && acc[e] > l1) { l1 = acc[e]; e1 = e; }
        w0 = 1.f / (1.f + __expf(l1 - l0));   // renormalized top-2 softmax
        bb = e0 * 8 + e1;                      // ordered pair bucket
        atomicAdd(&h[bb], 1);
    }
    __syncthreads();
    if (tid < NB) {
        int i = (tid + blockIdx.x) & (NB - 1);   // stagger start counter
        int c = h[i];
        if (c) base[i] = atomicAdd(&cnt[i * CSTR], c);
        h[i] = 0;
    }
    __syncthreads();
    if (j == 0) {
        int o = atomicAdd(&h[bb], 1);
        rt[bb * TOKENS + base[bb] + o] = ((unsigned)t << 16) | (unsigned)f2h(w0);
    }
}

// ---------------------------------------------------------------------------
// R16 expert: 512 threads / 8 waves per block (2x the R14 wave parallelism).
// cntS LDS stage restored (R15's serial global search cost ~10us/block).
// Wave w computes BOTH experts over n-range [w*32, w*32+32) (4mt x 2nt):
// acc = 64 VGPR/wave, W-load chain = 32 loads/wave (half of R14).
// X staged once for all 8 chunks via global_load_lds (wave w stages chunk w's
// 4 slots; ONE barrier); W straight to VGPRs from chunk-major wpad.
// Out written ONCE. Bijective XCD swizzle for W L2 locality.
// ---------------------------------------------------------------------------
__global__ __launch_bounds__(512, 2) void expert_kernel(
    const unsigned short* __restrict__ xp,   // [TOKENS][256] bf16 K-padded
    const unsigned short* __restrict__ wp,   // [8][8 c][4 s][256 n][8] bf16
    const float* __restrict__ ebpad,         // [8][256] f32
    const int* __restrict__ flag,
    const int* __restrict__ cnt, const unsigned* __restrict__ rt,
    void* __restrict__ outv)
{
    __shared__ __align__(16) unsigned short Xc[NCHUNK][4][64][8];  // 32 KB
    __shared__ int cntS[NB];

    const bool f32o = (*flag != 0);
    int tid = threadIdx.x;
    if (tid < NB) cntS[tid] = cnt[tid * CSTR];
    __syncthreads();

    // XCD-aware bijective swizzle (gridDim.x % 8 == 0 by construction)
    int nwg = gridDim.x;
    int fid = blockIdx.x;
    if ((nwg & 7) == 0)
        fid = (blockIdx.x & 7) * (nwg >> 3) + (blockIdx.x >> 3);

    // flat tile id -> (bucket, tile), search in LDS
    int b = -1, t = 0, accn = 0;
    for (int i = 0; i < NB; i++) {
        int ti = (cntS[i] + 63) >> 6;
        if (fid < accn + ti) { b = i; t = fid - accn; break; }
        accn += ti;
    }
    if (b < 0) return;
    int e0 = b >> 3, e1 = b & 7;
    int ne = cntS[b];
    int m0 = t * TILE_M;
    int rows = min(TILE_M, ne - m0);

    int lane = tid & 63;
    int w    = tid >> 6;          // wave id 0..7

    // token list in registers: lane l holds tile-row l
    unsigned rvp = rt[b * TOKENS + min(m0 + lane, ne - 1)];
    int   tokL = (int)(rvp >> 16);
    float w0L  = h2f((unsigned short)(rvp & 0xFFFFu));

    // X staging: wave w stages chunk w's 4 slots (lane l -> row l), 1 barrier
    const unsigned short* xbase = xp + (long)tokL * DP;
    #pragma unroll
    for (int i = 0; i < 4; i++)
        gload_lds16(xbase + w * BK + i * 8, &Xc[w][i][0][0]);
    __syncthreads();

    int frow = lane & 15;
    int slot = lane >> 4;
    // W fragment bases: elem off = e*65536 + c*8192 + slot*2048 + n*8,
    // n = w*32 + nt*16 + frow
    const unsigned short* wb0 = wp + (long)e0 * 65536 + slot * 2048
                                   + (w * 32 + frow) * 8;
    const unsigned short* wb1 = wp + (long)e1 * 65536 + slot * 2048
                                   + (w * 32 + frow) * 8;

    f32x4 acc0[4][2] = {};
    f32x4 acc1[4][2] = {};

    #pragma unroll
    for (int c = 0; c < NCHUNK; c++) {
        bf16x8 a[4], b0[2], b1[2];
        #pragma unroll
        for (int mt = 0; mt < 4; mt++)
            a[mt] = *(const bf16x8*)&Xc[c][slot][mt * 16 + frow][0];
        #pragma unroll
        for (int nt = 0; nt < 2; nt++) {
            b0[nt] = *(const bf16x8*)&wb0[c * 8192 + nt * 128];
            b1[nt] = *(const bf16x8*)&wb1[c * 8192 + nt * 128];
        }
        #pragma unroll
        for (int nt = 0; nt < 2; nt++)
            #pragma unroll
            for (int mt = 0; mt < 4; mt++) {
                acc0[mt][nt] = __builtin_amdgcn_mfma_f32_16x16x32_bf16(
                    a[mt], b0[nt], acc0[mt][nt], 0, 0, 0);
                acc1[mt][nt] = __builtin_amdgcn_mfma_f32_16x16x32_bf16(
                    a[mt], b1[nt], acc1[mt][nt], 0, 0, 0);
            }
    }

    // Epilogue: C/D layout col=lane&15, row=(lane>>4)*4+r  [m89-verified]
    int colg = lane & 15;
    int rq   = (lane >> 4) << 2;
    float b0n[2], b1n[2];
    #pragma unroll
    for (int nt = 0; nt < 2; nt++) {
        int n = w * 32 + nt * 16 + colg;
        b0n[nt] = ebpad[e0 * DP + n];
        b1n[nt] = ebpad[e1 * DP + n];
    }
    #pragma unroll
    for (int mt = 0; mt < 4; mt++) {
        #pragma unroll
        for (int r = 0; r < 4; r++) {
            int m = mt * 16 + rq + r;
            int   tok = __shfl(tokL, m);   // all lanes active here
            float w0  = __shfl(w0L, m);
            float w1  = 1.f - w0;
            if (m < rows) {
                #pragma unroll
                for (int nt = 0; nt < 2; nt++) {
                    int n = w * 32 + nt * 16 + colg;
                    if (n < Dm) {
                        float val = (acc0[mt][nt][r] + b0n[nt]) * w0
                                  + (acc1[mt][nt][r] + b1n[nt]) * w1;
                        long idx = (long)tok * Dm + n;
                        if (f32o) ((float*)outv)[idx] = val;
                        else      ((unsigned short*)outv)[idx] = f2b(val);
                    }
                }
            }
        }
    }
}

// ---------------------------------------------------------------------------
// Fallback path (R10-proven) for small workspaces — unchanged.
// ---------------------------------------------------------------------------
__global__ void detect_kernel(const unsigned short* __restrict__ x, int* flag,
                              int* __restrict__ cnt) {
    int lane = threadIdx.x;   // 64 threads
    cnt[lane] = 0;
    int hits = 0;
    for (int i = lane; i < 2048; i += 64) {
        unsigned e = (x[i] >> 7) & 0xFFu;
        if (e >= 0xC0u) hits++;
    }
    #pragma unroll
    for (int off = 32; off >= 1; off >>= 1) hits += __shfl_xor(hits, off, 64);
    if (lane == 0) flag[0] = (hits > 8) ? 1 : 0;
}

__global__ void init_kernel(int* cnt) {
    if (threadIdx.x < 16) cnt[threadIdx.x] = 0;
}

__global__ void zero_kernel(void* outv, const int* flag, int nelem) {
    long i = (long)blockIdx.x * blockDim.x + threadIdx.x;
    long stride = (long)gridDim.x * blockDim.x;
    if (*flag) {
        float* o = (float*)outv;
        for (; i < nelem; i += stride) o[i] = 0.f;
    } else {
        unsigned* o = (unsigned*)outv;
        long n = nelem >> 1;
        for (; i < n; i += stride) o[i] = 0u;
    }
}

template<bool FP32>
__global__ __launch_bounds__(256) void gate_fb_kernel(
    const void* __restrict__ xv, const void* __restrict__ gwv,
    const void* __restrict__ gbv, const int* __restrict__ flag,
    int* __restrict__ cnt, unsigned* __restrict__ rt, int cap)
{
    if ((*flag != 0) != FP32) return;
    __shared__ unsigned rv[256];
    __shared__ int h[16];
    __shared__ int base[16];

    int tid = threadIdx.x;
    if (tid < 16) h[tid] = 0;
    int t = blockIdx.x * 256 + tid;

    float acc[NE];
    #pragma unroll
    for (int e = 0; e < NE; e++)
        acc[e] = FP32 ? ((const float*)gbv)[e]
                      : b2f(((const unsigned short*)gbv)[e]);

    if (FP32) {
        const float* xf  = (const float*)xv + (long)t * Dm;
        const float* gwf = (const float*)gwv;
        for (int k = 0; k < Dm; k += 8) {
            float4 xa = *(const float4*)&xf[k];
            float4 xb = *(const float4*)&xf[k + 4];
            #pragma unroll
            for (int e = 0; e < NE; e++) {
                float4 ga = *(const float4*)&gwf[e * Dm + k];
                float4 gb = *(const float4*)&gwf[e * Dm + k + 4];
                acc[e] += xa.x * ga.x + xa.y * ga.y + xa.z * ga.z + xa.w * ga.w
                        + xb.x * gb.x + xb.y * gb.y + xb.z * gb.z + xb.w * gb.w;
            }
        }
    } else {
        const unsigned short* xb  = (const unsigned short*)xv + (long)t * Dm;
        const unsigned short* gwb = (const unsigned short*)gwv;
        for (int k = 0; k < Dm; k += 8) {
            uint4 xq = *(const uint4*)&xb[k];
            float x0 = b2f_lo(xq.x), x1 = b2f_hi(xq.x);
            float x2 = b2f_lo(xq.y), x3 = b2f_hi(xq.y);
            float x4 = b2f_lo(xq.z), x5 = b2f_hi(xq.z);
            float x6 = b2f_lo(xq.w), x7 = b2f_hi(xq.w);
            #pragma unroll
            for (int e = 0; e < NE; e++) {
                uint4 gq = *(const uint4*)&gwb[e * Dm + k];
                acc[e] += x0 * b2f_lo(gq.x) + x1 * b2f_hi(gq.x)
                        + x2 * b2f_lo(gq.y) + x3 * b2f_hi(gq.y)
                        + x4 * b2f_lo(gq.z) + x5 * b2f_hi(gq.z)
                        + x6 * b2f_lo(gq.w) + x7 * b2f_hi(gq.w);
            }
        }
    }

    float l0 = -1e30f; int e0 = 0;
    #pragma unroll
    for (int e = 0; e < NE; e++) if (acc[e] > l0) { l0 = acc[e]; e0 = e; }
    float l1 = -1e30f; int e1 = 0;
    #pragma unroll
    for (int e = 0; e < NE; e++) if (e != e0 && acc[e] > l1) { l1 = acc[e]; e1 = e; }
    float w0 = 1.f / (1.f + __expf(l1 - l0));

    rv[tid] = ((unsigned)e1 << 20) | ((unsigned)e0 << 16) | (unsigned)f2h(w0);
    __syncthreads();

    {
        unsigned v = rv[tid];
        atomicAdd(&h[(v >> 16) & 7], 1);
        atomicAdd(&h[8 + ((v >> 20) & 7)], 1);
    }
    __syncthreads();

    if (tid < 16) {
        base[tid] = atomicAdd(&cnt[tid], h[tid]);
        h[tid] = 0;
    }
    __syncthreads();

    {
        unsigned v = rv[tid];
        int tt = blockIdx.x * 256 + tid;
        int a0 = (v >> 16) & 7;
        int a1 = (v >> 20) & 7;
        unsigned short hw0 = (unsigned short)(v & 0xFFFFu);
        int o0 = atomicAdd(&h[a0], 1);
        int p0 = base[a0] + o0;
        if (p0 < cap) rt[a0 * cap + p0] = ((unsigned)tt << 16) | hw0;
        int o1 = atomicAdd(&h[8 + a1], 1);
        int p1 = base[8 + a1] + o1;
        if (p1 < cap) rt[(8 + a1) * cap + p1] = ((unsigned)tt << 16) | (unsigned)f2h(1.f - h2f(hw0));
    }
}

template<bool FP32>
__global__ __launch_bounds__(256) void expert_fb_kernel(
    const void* __restrict__ xv, const void* __restrict__ ewv,
    const void* __restrict__ ebv, const int* __restrict__ flag,
    const int* __restrict__ cnt, const unsigned* __restrict__ rt, int cap,
    void* __restrict__ outv, int slotBase, int accumulate)
{
    if ((*flag != 0) != FP32) return;
    int e = blockIdx.y;
    int tile = blockIdx.x;
    int bucket = slotBase + e;
    int ne = min(cnt[bucket], cap);
    int m0 = tile * TILE_M;
    if (m0 >= ne) return;
    int rows = min(TILE_M, ne - m0);

    __shared__ __align__(16) unsigned short Wcf[2][256][40];
    __shared__ __align__(16) unsigned short Xcf[2][TILE_M][40];
    __shared__ int   tokS[TILE_M];
    __shared__ float twS[TILE_M];

    int tid = threadIdx.x;
    if (tid < TILE_M) {
        int i = min(m0 + tid, ne - 1);
        unsigned v = rt[bucket * cap + i];
        tokS[tid] = (int)(v >> 16);
        twS[tid]  = (tid < rows) ? h2f((unsigned short)(v & 0xFFFFu)) : 0.f;
    }
    __syncthreads();

    int srow = tid >> 2;
    int part = tid & 3;

    auto stage = [&](int c, int buf) {
        int kk = c * BK + part * 8;
        bool kvalid = (kk < Dm);
        if (FP32) {
            const float* xf = (const float*)xv;
            const float* Wf = (const float*)ewv + e * Dm * Dm;
            uint4 xq = make_uint4(0, 0, 0, 0);
            if (kvalid) {
                const float* s = &xf[(long)tokS[srow] * Dm + kk];
                xq = pack8(*(const float4*)s, *(const float4*)(s + 4));
            }
            *(uint4*)&Xcf[buf][srow][part * 8] = xq;
            #pragma unroll
            for (int it = 0; it < 4; it++) {
                int n = srow + it * 64;
                uint4 wq = make_uint4(0, 0, 0, 0);
                if (kvalid && n < Dm) {
                    const float* s = &Wf[(long)n * Dm + kk];
                    wq = pack8(*(const float4*)s, *(const float4*)(s + 4));
                }
                *(uint4*)&Wcf[buf][n][part * 8] = wq;
            }
        } else {
            const unsigned short* xb = (const unsigned short*)xv;
            const unsigned short* Wb = (const unsigned short*)ewv + e * Dm * Dm;
            uint4 xq = make_uint4(0, 0, 0, 0);
            if (kvalid) xq = *(const uint4*)&xb[(long)tokS[srow] * Dm + kk];
            *(uint4*)&Xcf[buf][srow][part * 8] = xq;
            #pragma unroll
            for (int it = 0; it < 4; it++) {
                int n = srow + it * 64;
                uint4 wq = make_uint4(0, 0, 0, 0);
                if (kvalid && n < Dm) wq = *(const uint4*)&Wb[(long)n * Dm + kk];
                *(uint4*)&Wcf[buf][n][part * 8] = wq;
            }
        }
    };

    int lane = tid & 63;
    int wv   = tid >> 6;
    int frow = lane & 15;
    int koff = (lane >> 4) * 8;

    f32x4 acc[TILE_M / 16][4] = {};

    stage(0, 0);
    __syncthreads();
    for (int c = 0; c < NCHUNK; c++) {
        int buf = c & 1;
        bf16x8 a[TILE_M / 16], b[4];
        #pragma unroll
        for (int mt = 0; mt < TILE_M / 16; mt++)
            a[mt] = *(const bf16x8*)&Xcf[buf][mt * 16 + frow][koff];
        #pragma unroll
        for (int nt = 0; nt < 4; nt++)
            b[nt] = *(const bf16x8*)&Wcf[buf][wv * 64 + nt * 16 + frow][koff];
        if (c + 1 < NCHUNK) stage(c + 1, (c + 1) & 1);
        #pragma unroll
        for (int mt = 0; mt < TILE_M / 16; mt++)
            #pragma unroll
            for (int nt = 0; nt < 4; nt++)
                acc[mt][nt] = __builtin_amdgcn_mfma_f32_16x16x32_bf16(
                    a[mt], b[nt], acc[mt][nt], 0, 0, 0);
        __syncthreads();
    }

    int colg  = lane & 15;
    int rquad = (lane >> 4) * 4;
    #pragma unroll
    for (int nt = 0; nt < 4; nt++) {
        int n = wv * 64 + nt * 16 + colg;
        if (n >= Dm) continue;
        float bnv = FP32 ? ((const float*)ebv)[e * Dm + n]
                         : b2f(((const unsigned short*)ebv)[e * Dm + n]);
        #pragma unroll
        for (int mt = 0; mt < TILE_M / 16; mt++) {
            #pragma unroll
            for (int r = 0; r < 4; r++) {
                int m = mt * 16 + rquad + r;
                if (m < rows) {
                    float val = (acc[mt][nt][r] + bnv) * twS[m];
                    long idx = (long)tokS[m] * Dm + n;
                    if (FP32) {
                        float* o = (float*)outv + idx;
                        *o = accumulate ? (*o + val) : val;
                    } else {
                        unsigned short* o = (unsigned short*)outv + idx;
                        *o = accumulate ? f2b(b2f(*o) + val) : f2b(val);
                    }
                }
            }
        }
    }
}

extern "C" void kernel_launch(void* const* d_in, const int* in_sizes, int n_in,
                              void* d_out, int out_size, void* d_ws, size_t ws_size,
                              hipStream_t stream) {
    const void* x  = d_in[0];
    const void* gw = d_in[1];
    const void* gb = d_in[2];
    const void* ew = d_in[3];
    const void* eb = d_in[4];

    char* ws = (char*)d_ws;
    int* flag = (int*)ws;                 // [0]        dtype flag
    int* cnt  = (int*)(ws + 64);          // [64*CSTR]  padded bucket counters

    // R16 fast-path workspace layout
    const size_t EB_OFF = 64 + (size_t)NB * CSTR * 4;            // 4160
    const size_t RT_OFF = EB_OFF + (size_t)NE * DP * 4;          // 12352
    const size_t XP_OFF = RT_OFF + (size_t)NB * TOKENS * 4;      // +8 MiB
    const size_t WP_OFF = XP_OFF + (size_t)TOKENS * DP * 2;      // +16 MiB
    const size_t NEEDED = WP_OFF + (size_t)NE * NCHUNK * 8192 * 2; // ≈ 26.2 MB

    if (ws_size >= NEEDED) {
        float*          ebpad = (float*)(ws + EB_OFF);
        unsigned*       rt    = (unsigned*)(ws + RT_OFF);
        unsigned short* xpad  = (unsigned short*)(ws + XP_OFF);
        unsigned short* wpad  = (unsigned short*)(ws + WP_OFF);

        wconv_kernel<<<256, 256, 0, stream>>>(ew, eb, (const unsigned short*)x,
                                              flag, cnt, wpad, ebpad);
        gate_kernel<<<TOKENS / 32, 256, 0, stream>>>(x, gw, gb, cnt, rt, xpad);
        // worst-case flat tiles: 32768/64 full + 64 partials = 576 (mult of 8)
        expert_kernel<<<TOKENS / TILE_M + NB, 512, 0, stream>>>(
            xpad, wpad, ebpad, flag, cnt, rt, d_out);
    } else {
        // ---------------- R10 fallback (proven) ----------------
        unsigned* rt = (unsigned*)(ws + 128);
        long capl = ((long)ws_size - 128) / (16 * sizeof(unsigned));
        if (capl > TOKENS) capl = TOKENS;
        if (capl < 64) capl = 64;
        int cap = (int)capl;
        int tiles = (cap + TILE_M - 1) / TILE_M;
        bool lossless = (cap >= TOKENS);
        int acc0 = lossless ? 0 : 1;

        detect_kernel<<<1, 64, 0, stream>>>((const unsigned short*)x, flag, cnt);
        init_kernel<<<1, 64, 0, stream>>>(cnt);
        gate_fb_kernel<false><<<TOKENS / 256, 256, 0, stream>>>(x, gw, gb, flag, cnt, rt, cap);
        gate_fb_kernel<true ><<<TOKENS / 256, 256, 0, stream>>>(x, gw, gb, flag, cnt, rt, cap);
        if (!lossless)
            zero_kernel<<<1024, 256, 0, stream>>>(d_out, flag, out_size);
        expert_fb_kernel<false><<<dim3(tiles, NE), 256, 0, stream>>>(x, ew, eb, flag, cnt, rt, cap, d_out, 0, acc0);
        expert_fb_kernel<true ><<<dim3(tiles, NE), 256, 0, stream>>>(x, ew, eb, flag, cnt, rt, cap, d_out, 0, acc0);
        expert_fb_kernel<false><<<dim3(tiles, NE), 256, 0, stream>>>(x, ew, eb, flag, cnt, rt, cap, d_out, 8, 1);
        expert_fb_kernel<true ><<<dim3(tiles, NE), 256, 0, stream>>>(x, ew, eb, flag, cnt, rt, cap, d_out, 8, 1);
    }
}